// Round 6
// baseline (114.883 us; speedup 1.0000x reference)
//
#include <hip/hip_runtime.h>

typedef _Float16 half4 __attribute__((ext_vector_type(4)));
typedef float floatx4 __attribute__((ext_vector_type(4)));

#define U_RESV 400
#define A_RESV 50

// f16 weight blob layout in d_ws (halves):
//   [0    ..  768) : W0  32 rows x stride 24
//   [768  .. 1920) : W1  32 rows x stride 36
//   [1920 .. 3072) : W2  32 rows x stride 36
//   [3072 .. 3648) : W3  16 rows x stride 36 (rows>=3 / cols>=32 zero)
#define WTOT 3648   // halves; 7296 B = 456 x 16 B

__device__ __forceinline__ float clamp01(float x) { return fminf(fmaxf(x, 0.0f), 1.0f); }

__device__ __forceinline__ floatx4 mfma16(half4 a, half4 b, floatx4 c) {
    return __builtin_amdgcn_mfma_f32_16x16x16f16(a, b, c, 0, 0, 0);
}
__device__ __forceinline__ half4 zero4() {
    half4 h; h[0] = h[1] = h[2] = h[3] = (_Float16)0.f; return h;
}

// ---- pre-kernel: f32 weights -> f16 blob in ws (runs once per launch) ----
__global__ __launch_bounds__(256) void wprep_kernel(
    const float* __restrict__ W0, const float* __restrict__ W1,
    const float* __restrict__ W2, const float* __restrict__ W3,
    _Float16* __restrict__ wsw) {
    for (int i = threadIdx.x; i < WTOT; i += 256) {
        float v;
        if (i < 768) {
            v = W0[i];                       // dense 32x24
        } else if (i < 1920) {
            int j = i - 768, r = j / 36, c = j - r * 36;
            v = (c < 32) ? W1[r * 32 + c] : 0.f;
        } else if (i < 3072) {
            int j = i - 1920, r = j / 36, c = j - r * 36;
            v = (c < 32) ? W2[r * 32 + c] : 0.f;
        } else {
            int j = i - 3072, r = j / 36, c = j - r * 36;
            v = (r < 3 && c < 32) ? W3[r * 32 + c] : 0.f;
        }
        wsw[i] = (_Float16)v;
    }
}

// Two lanes per point: even lane = texel ch 0-3, odd lane = ch 4-7 (64B-line pair-coalesced).
// MFMA maps (verified R4/R5, 16x16x16 f16):
//   A: lane 16q+c holds A[row=c][k=4q+e];  B: lane 16q+c holds B[k=4q+e][col=c]
//   D: lane 16q+c reg r holds D[row=4q+r][col=c]
// Chain identity: D reg r == next-layer B elem e. MLP chains in registers.

__global__ __launch_bounds__(256, 8) void tpmlp_kernel(
    const float* __restrict__ x,
    const float* __restrict__ u_plane,
    const float* __restrict__ h_plane,
    const float* __restrict__ d_plane,
    const _Float16* __restrict__ wsw,
    float* __restrict__ out) {
    const int tid  = threadIdx.x;
    const int lane = tid & 63;
    const int wv   = tid >> 6;
    const int hf   = lane & 1;
    const int pidx = wv * 32 + (lane >> 1);
    const int q    = lane >> 4;
    const int c15  = lane & 15;

    __shared__ __align__(16) _Float16 fl[128 * 28];   // feat: stride 56 B
    __shared__ __align__(16) _Float16 wl[WTOT];       // weight blob

    // ---- stage weights from ws (2 x dwordx4 per thread) ----
    {
        const uint4* src = (const uint4*)wsw;
        uint4* dst = (uint4*)wl;
        dst[tid] = src[tid];                    // 456 chunks of 16 B
        if (tid < 456 - 256) dst[256 + tid] = src[256 + tid];
    }

    // ---- x load + gather addresses ----
    const size_t P = (size_t)blockIdx.x * 128 + pidx;
    const float2* xp = (const float2*)(x + P * 6);
    float2 p01v = xp[0], p23v = xp[1], p45v = xp[2];

    int oU0, oU1, oU2, oU3;  float uw00, uw10, uw01, uw11;
    {
        float u = clamp01(p01v.x) * (float)(U_RESV - 1);
        float v = clamp01(p01v.y) * (float)(U_RESV - 1);
        float x0f = floorf(u), y0f = floorf(v);
        int x0 = (int)x0f, y0 = (int)y0f;
        int x1 = min(x0 + 1, U_RESV - 1), y1 = min(y0 + 1, U_RESV - 1);
        float ur = u - x0f, vr = v - y0f;
        uw00 = (1.0f - ur) * (1.0f - vr); uw10 = ur * (1.0f - vr);
        uw01 = (1.0f - ur) * vr;          uw11 = ur * vr;
        oU0 = (y0 * U_RESV + x0) * 8 + hf * 4;
        oU1 = (y0 * U_RESV + x1) * 8 + hf * 4;
        oU2 = (y1 * U_RESV + x0) * 8 + hf * 4;
        oU3 = (y1 * U_RESV + x1) * 8 + hf * 4;
    }
    int oH0, oH1, oH2, oH3;  float hw00, hw10, hw01, hw11;
    {
        float uu = p23v.y, vv = p23v.x;
        float uf = uu - floorf(uu);
        float u = uf * (float)A_RESV;                 // u in [0, 50) strictly
        float v = clamp01(vv) * (float)(A_RESV - 1);
        float x0f = floorf(u), y0f = floorf(v);
        int x0 = (int)x0f;                            // 0..49, % is a no-op
        int x1 = x0 + 1; if (x1 == A_RESV) x1 = 0;
        int y0 = (int)y0f;
        int y1 = min(y0 + 1, A_RESV - 1);
        float ur = u - x0f, vr = v - y0f;
        hw00 = (1.0f - ur) * (1.0f - vr); hw10 = ur * (1.0f - vr);
        hw01 = (1.0f - ur) * vr;          hw11 = ur * vr;
        oH0 = (y0 * A_RESV + x0) * 8 + hf * 4;
        oH1 = (y0 * A_RESV + x1) * 8 + hf * 4;
        oH2 = (y1 * A_RESV + x0) * 8 + hf * 4;
        oH3 = (y1 * A_RESV + x1) * 8 + hf * 4;
    }
    int oD0, oD1, oD2, oD3;  float dw00, dw10, dw01, dw11;
    {
        float uu = p45v.y, vv = p45v.x;
        float uf = uu - floorf(uu);
        float u = uf * (float)A_RESV;
        float v = clamp01(vv) * (float)(A_RESV - 1);
        float x0f = floorf(u), y0f = floorf(v);
        int x0 = (int)x0f;
        int x1 = x0 + 1; if (x1 == A_RESV) x1 = 0;
        int y0 = (int)y0f;
        int y1 = min(y0 + 1, A_RESV - 1);
        float ur = u - x0f, vr = v - y0f;
        dw00 = (1.0f - ur) * (1.0f - vr); dw10 = ur * (1.0f - vr);
        dw01 = (1.0f - ur) * vr;          dw11 = ur * vr;
        oD0 = (y0 * A_RESV + x0) * 8 + hf * 4;
        oD1 = (y0 * A_RESV + x1) * 8 + hf * 4;
        oD2 = (y1 * A_RESV + x0) * 8 + hf * 4;
        oD3 = (y1 * A_RESV + x1) * 8 + hf * 4;
    }

    // ---- issue all 12 independent 16B texel loads ----
    const float4 tU0 = *(const float4*)(u_plane + oU0);
    const float4 tU1 = *(const float4*)(u_plane + oU1);
    const float4 tU2 = *(const float4*)(u_plane + oU2);
    const float4 tU3 = *(const float4*)(u_plane + oU3);
    const float4 tH0 = *(const float4*)(h_plane + oH0);
    const float4 tH1 = *(const float4*)(h_plane + oH1);
    const float4 tH2 = *(const float4*)(h_plane + oH2);
    const float4 tH3 = *(const float4*)(h_plane + oH3);
    const float4 tD0 = *(const float4*)(d_plane + oD0);
    const float4 tD1 = *(const float4*)(d_plane + oD1);
    const float4 tD2 = *(const float4*)(d_plane + oD2);
    const float4 tD3 = *(const float4*)(d_plane + oD3);

    // ---- weighted sums (exact R1/R4/R5 per-channel FMA order) ----
    float fU[4], fH[4], fD[4];
    {
        const float* a = (const float*)&tU0; const float* b = (const float*)&tU1;
        const float* c = (const float*)&tU2; const float* d = (const float*)&tU3;
#pragma unroll
        for (int i = 0; i < 4; ++i) {
            float r = a[i] * uw00;
            r = fmaf(b[i], uw10, r);
            r = fmaf(c[i], uw01, r);
            r = fmaf(d[i], uw11, r);
            fU[i] = r;
        }
    }
    {
        const float* a = (const float*)&tH0; const float* b = (const float*)&tH1;
        const float* c = (const float*)&tH2; const float* d = (const float*)&tH3;
#pragma unroll
        for (int i = 0; i < 4; ++i) {
            float r = a[i] * hw00;
            r = fmaf(b[i], hw10, r);
            r = fmaf(c[i], hw01, r);
            r = fmaf(d[i], hw11, r);
            fH[i] = r;
        }
    }
    {
        const float* a = (const float*)&tD0; const float* b = (const float*)&tD1;
        const float* c = (const float*)&tD2; const float* d = (const float*)&tD3;
#pragma unroll
        for (int i = 0; i < 4; ++i) {
            float r = a[i] * dw00;
            r = fmaf(b[i], dw10, r);
            r = fmaf(c[i], dw01, r);
            r = fmaf(d[i], dw11, r);
            fD[i] = r;
        }
    }

    // ---- feat -> f16 -> LDS ----
    {
        _Float16* row = fl + pidx * 28;
        half4 hU, hH, hD;
#pragma unroll
        for (int i = 0; i < 4; ++i) {
            hU[i] = (_Float16)fU[i];
            hH[i] = (_Float16)fH[i];
            hD[i] = (_Float16)fD[i];
        }
        *(half4*)(row + hf * 4)      = hU;
        *(half4*)(row + 8 + hf * 4)  = hH;
        *(half4*)(row + 16 + hf * 4) = hD;
    }
    __syncthreads();

    // ---- MLP: wave owns 32 points, j-tiles {0,1} ----
    floatx4 zf; zf[0] = 0.f; zf[1] = 0.f; zf[2] = 0.f; zf[3] = 0.f;
    const _Float16* wb = fl + (size_t)wv * 32 * 28;
    const _Float16* w0l = wl;
    const _Float16* w1l = wl + 768;
    const _Float16* w2l = wl + 1920;
    const _Float16* w3l = wl + 3072;

    half4 b0[2], b1[2];
#pragma unroll
    for (int j = 0; j < 2; ++j) {
        const _Float16* r = wb + (size_t)(j * 16 + c15) * 28;
        b0[j] = *(const half4*)(r + q * 4);
        b1[j] = (q < 2) ? *(const half4*)(r + 16 + q * 4) : zero4();
    }

    floatx4 cc[2][2];
#pragma unroll
    for (int m = 0; m < 2; ++m) {
        half4 a0 = *(const half4*)(w0l + (size_t)(16 * m + c15) * 24 + q * 4);
        half4 a1 = (q < 2) ? *(const half4*)(w0l + (size_t)(16 * m + c15) * 24 + 16 + q * 4) : zero4();
#pragma unroll
        for (int j = 0; j < 2; ++j)
            cc[m][j] = mfma16(a1, b1[j], mfma16(a0, b0[j], zf));
    }
#pragma unroll
    for (int j = 0; j < 2; ++j)
#pragma unroll
        for (int e = 0; e < 4; ++e) {
            b0[j][e] = (_Float16)fmaxf(cc[0][j][e], 0.f);
            b1[j][e] = (_Float16)fmaxf(cc[1][j][e], 0.f);
        }

#pragma unroll
    for (int m = 0; m < 2; ++m) {
        half4 a0 = *(const half4*)(w1l + (size_t)(16 * m + c15) * 36 + q * 4);
        half4 a1 = *(const half4*)(w1l + (size_t)(16 * m + c15) * 36 + 16 + q * 4);
#pragma unroll
        for (int j = 0; j < 2; ++j)
            cc[m][j] = mfma16(a1, b1[j], mfma16(a0, b0[j], zf));
    }
#pragma unroll
    for (int j = 0; j < 2; ++j)
#pragma unroll
        for (int e = 0; e < 4; ++e) {
            b0[j][e] = (_Float16)fmaxf(cc[0][j][e], 0.f);
            b1[j][e] = (_Float16)fmaxf(cc[1][j][e], 0.f);
        }

#pragma unroll
    for (int m = 0; m < 2; ++m) {
        half4 a0 = *(const half4*)(w2l + (size_t)(16 * m + c15) * 36 + q * 4);
        half4 a1 = *(const half4*)(w2l + (size_t)(16 * m + c15) * 36 + 16 + q * 4);
#pragma unroll
        for (int j = 0; j < 2; ++j)
            cc[m][j] = mfma16(a1, b1[j], mfma16(a0, b0[j], zf));
    }
#pragma unroll
    for (int j = 0; j < 2; ++j)
#pragma unroll
        for (int e = 0; e < 4; ++e) {
            b0[j][e] = (_Float16)fmaxf(cc[0][j][e], 0.f);
            b1[j][e] = (_Float16)fmaxf(cc[1][j][e], 0.f);
        }

    floatx4 c3[2];
    {
        half4 a0 = *(const half4*)(w3l + (size_t)c15 * 36 + q * 4);
        half4 a1 = *(const half4*)(w3l + (size_t)c15 * 36 + 16 + q * 4);
#pragma unroll
        for (int j = 0; j < 2; ++j)
            c3[j] = mfma16(a1, b1[j], mfma16(a0, b0[j], zf));
    }

    if (lane < 16) {
        const size_t base = (size_t)blockIdx.x * 128 + (size_t)wv * 32;
#pragma unroll
        for (int j = 0; j < 2; ++j) {
            size_t p = base + (size_t)j * 16 + lane;
            float* o = out + p * 3;
            o[0] = c3[j][0];
            o[1] = c3[j][1];
            o[2] = c3[j][2];
        }
    }
}

extern "C" void kernel_launch(void* const* d_in, const int* in_sizes, int n_in,
                              void* d_out, int out_size, void* d_ws, size_t ws_size,
                              hipStream_t stream) {
    const float* x       = (const float*)d_in[0];
    const float* u_plane = (const float*)d_in[1];
    const float* h_plane = (const float*)d_in[2];
    const float* d_plane = (const float*)d_in[3];
    const float* W0      = (const float*)d_in[4];
    const float* W1      = (const float*)d_in[5];
    const float* W2      = (const float*)d_in[6];
    const float* W3      = (const float*)d_in[7];
    float* out = (float*)d_out;
    _Float16* wsw = (_Float16*)d_ws;

    wprep_kernel<<<1, 256, 0, stream>>>(W0, W1, W2, W3, wsw);

    int n = in_sizes[0] / 6;          // 2^21
    int grid = n / 128;               // 128 points per block
    tpmlp_kernel<<<grid, 256, 0, stream>>>(x, u_plane, h_plane, d_plane, wsw, out);
}

// Round 7
// 94.916 us; speedup vs baseline: 1.2104x; 1.2104x over previous
//
#include <hip/hip_runtime.h>

typedef _Float16 half4 __attribute__((ext_vector_type(4)));
typedef float floatx4 __attribute__((ext_vector_type(4)));

#define U_RESV 400
#define A_RESV 50

// f16 weight blob layout in d_ws (halves):
//   [0    ..  768) : W0  32 rows x stride 24
//   [768  .. 1920) : W1  32 rows x stride 36
//   [1920 .. 3072) : W2  32 rows x stride 36
//   [3072 .. 3648) : W3  16 rows x stride 36 (rows>=3 / cols>=32 zero)
#define WTOT 3648   // halves; 7296 B = 456 x 16 B

__device__ __forceinline__ float clamp01(float x) { return fminf(fmaxf(x, 0.0f), 1.0f); }

__device__ __forceinline__ floatx4 mfma16(half4 a, half4 b, floatx4 c) {
    return __builtin_amdgcn_mfma_f32_16x16x16f16(a, b, c, 0, 0, 0);
}
__device__ __forceinline__ half4 zero4() {
    half4 h; h[0] = h[1] = h[2] = h[3] = (_Float16)0.f; return h;
}

// ---- pre-kernel: f32 weights -> f16 blob in ws (runs once per launch) ----
__global__ __launch_bounds__(256) void wprep_kernel(
    const float* __restrict__ W0, const float* __restrict__ W1,
    const float* __restrict__ W2, const float* __restrict__ W3,
    _Float16* __restrict__ wsw) {
    for (int i = threadIdx.x; i < WTOT; i += 256) {
        float v;
        if (i < 768) {
            v = W0[i];
        } else if (i < 1920) {
            int j = i - 768, r = j / 36, c = j - r * 36;
            v = (c < 32) ? W1[r * 32 + c] : 0.f;
        } else if (i < 3072) {
            int j = i - 1920, r = j / 36, c = j - r * 36;
            v = (c < 32) ? W2[r * 32 + c] : 0.f;
        } else {
            int j = i - 3072, r = j / 36, c = j - r * 36;
            v = (r < 3 && c < 32) ? W3[r * 32 + c] : 0.f;
        }
        wsw[i] = (_Float16)v;
    }
}

// Two lanes per point: even lane = texel ch 0-3, odd lane = ch 4-7 (line pair-coalesced).
// MFMA maps (verified R4/R5, 16x16x16 f16):
//   A: lane 16q+c holds A[row=c][k=4q+e];  B: lane 16q+c holds B[k=4q+e][col=c]
//   D: lane 16q+c reg r holds D[row=4q+r][col=c]
// Chain identity: D reg r == next-layer B elem e. MLP chains in registers.
// launch_bounds(256,4): VGPR cap 128 so all 12 texel loads stay in flight
// (R6's (256,8) cap=32 VGPR serialized the gather -> 125us regression).

__global__ __launch_bounds__(256, 4) void tpmlp_kernel(
    const float* __restrict__ x,
    const float* __restrict__ u_plane,
    const float* __restrict__ h_plane,
    const float* __restrict__ d_plane,
    const _Float16* __restrict__ wsw,
    float* __restrict__ out) {
    const int tid  = threadIdx.x;
    const int lane = tid & 63;
    const int wv   = tid >> 6;
    const int hf   = lane & 1;
    const int pidx = wv * 32 + (lane >> 1);
    const int q    = lane >> 4;
    const int c15  = lane & 15;

    __shared__ __align__(16) _Float16 fl[128 * 28];   // feat: stride 56 B
    __shared__ __align__(16) _Float16 wl[WTOT];       // weight blob

    // ---- x load + gather addresses ----
    const size_t P = (size_t)blockIdx.x * 128 + pidx;
    const float2* xp = (const float2*)(x + P * 6);
    float2 p01v = xp[0], p23v = xp[1], p45v = xp[2];

    int oU0, oU1, oU2, oU3;  float uw00, uw10, uw01, uw11;
    {
        float u = clamp01(p01v.x) * (float)(U_RESV - 1);
        float v = clamp01(p01v.y) * (float)(U_RESV - 1);
        float x0f = floorf(u), y0f = floorf(v);
        int x0 = (int)x0f, y0 = (int)y0f;
        int x1 = min(x0 + 1, U_RESV - 1), y1 = min(y0 + 1, U_RESV - 1);
        float ur = u - x0f, vr = v - y0f;
        uw00 = (1.0f - ur) * (1.0f - vr); uw10 = ur * (1.0f - vr);
        uw01 = (1.0f - ur) * vr;          uw11 = ur * vr;
        oU0 = (y0 * U_RESV + x0) * 8 + hf * 4;
        oU1 = (y0 * U_RESV + x1) * 8 + hf * 4;
        oU2 = (y1 * U_RESV + x0) * 8 + hf * 4;
        oU3 = (y1 * U_RESV + x1) * 8 + hf * 4;
    }
    int oH0, oH1, oH2, oH3;  float hw00, hw10, hw01, hw11;
    {
        float uu = p23v.y, vv = p23v.x;
        float uf = uu - floorf(uu);
        float u = uf * (float)A_RESV;                 // u in [0,50) strictly
        float v = clamp01(vv) * (float)(A_RESV - 1);
        float x0f = floorf(u), y0f = floorf(v);
        int x0 = (int)x0f;
        int x1 = x0 + 1; if (x1 == A_RESV) x1 = 0;
        int y0 = (int)y0f;
        int y1 = min(y0 + 1, A_RESV - 1);
        float ur = u - x0f, vr = v - y0f;
        hw00 = (1.0f - ur) * (1.0f - vr); hw10 = ur * (1.0f - vr);
        hw01 = (1.0f - ur) * vr;          hw11 = ur * vr;
        oH0 = (y0 * A_RESV + x0) * 8 + hf * 4;
        oH1 = (y0 * A_RESV + x1) * 8 + hf * 4;
        oH2 = (y1 * A_RESV + x0) * 8 + hf * 4;
        oH3 = (y1 * A_RESV + x1) * 8 + hf * 4;
    }
    int oD0, oD1, oD2, oD3;  float dw00, dw10, dw01, dw11;
    {
        float uu = p45v.y, vv = p45v.x;
        float uf = uu - floorf(uu);
        float u = uf * (float)A_RESV;
        float v = clamp01(vv) * (float)(A_RESV - 1);
        float x0f = floorf(u), y0f = floorf(v);
        int x0 = (int)x0f;
        int x1 = x0 + 1; if (x1 == A_RESV) x1 = 0;
        int y0 = (int)y0f;
        int y1 = min(y0 + 1, A_RESV - 1);
        float ur = u - x0f, vr = v - y0f;
        dw00 = (1.0f - ur) * (1.0f - vr); dw10 = ur * (1.0f - vr);
        dw01 = (1.0f - ur) * vr;          dw11 = ur * vr;
        oD0 = (y0 * A_RESV + x0) * 8 + hf * 4;
        oD1 = (y0 * A_RESV + x1) * 8 + hf * 4;
        oD2 = (y1 * A_RESV + x0) * 8 + hf * 4;
        oD3 = (y1 * A_RESV + x1) * 8 + hf * 4;
    }

    // ---- issue all 12 independent 16B texel loads (keep all in flight) ----
    const float4 tU0 = *(const float4*)(u_plane + oU0);
    const float4 tU1 = *(const float4*)(u_plane + oU1);
    const float4 tU2 = *(const float4*)(u_plane + oU2);
    const float4 tU3 = *(const float4*)(u_plane + oU3);
    const float4 tH0 = *(const float4*)(h_plane + oH0);
    const float4 tH1 = *(const float4*)(h_plane + oH1);
    const float4 tH2 = *(const float4*)(h_plane + oH2);
    const float4 tH3 = *(const float4*)(h_plane + oH3);
    const float4 tD0 = *(const float4*)(d_plane + oD0);
    const float4 tD1 = *(const float4*)(d_plane + oD1);
    const float4 tD2 = *(const float4*)(d_plane + oD2);
    const float4 tD3 = *(const float4*)(d_plane + oD3);

    // ---- stage weights from ws (independent; overlaps texel latency) ----
    {
        const uint4* src = (const uint4*)wsw;
        uint4* dst = (uint4*)wl;
        uint4 w_a = src[tid];
        uint4 w_b;
        if (tid < 456 - 256) w_b = src[256 + tid];
        dst[tid] = w_a;
        if (tid < 456 - 256) dst[256 + tid] = w_b;
    }

    // ---- weighted sums (exact R1/R4/R5 per-channel FMA order) ----
    float fU[4], fH[4], fD[4];
    {
        const float* a = (const float*)&tU0; const float* b = (const float*)&tU1;
        const float* c = (const float*)&tU2; const float* d = (const float*)&tU3;
#pragma unroll
        for (int i = 0; i < 4; ++i) {
            float r = a[i] * uw00;
            r = fmaf(b[i], uw10, r);
            r = fmaf(c[i], uw01, r);
            r = fmaf(d[i], uw11, r);
            fU[i] = r;
        }
    }
    {
        const float* a = (const float*)&tH0; const float* b = (const float*)&tH1;
        const float* c = (const float*)&tH2; const float* d = (const float*)&tH3;
#pragma unroll
        for (int i = 0; i < 4; ++i) {
            float r = a[i] * hw00;
            r = fmaf(b[i], hw10, r);
            r = fmaf(c[i], hw01, r);
            r = fmaf(d[i], hw11, r);
            fH[i] = r;
        }
    }
    {
        const float* a = (const float*)&tD0; const float* b = (const float*)&tD1;
        const float* c = (const float*)&tD2; const float* d = (const float*)&tD3;
#pragma unroll
        for (int i = 0; i < 4; ++i) {
            float r = a[i] * dw00;
            r = fmaf(b[i], dw10, r);
            r = fmaf(c[i], dw01, r);
            r = fmaf(d[i], dw11, r);
            fD[i] = r;
        }
    }

    // ---- feat -> f16 -> LDS ----
    {
        _Float16* row = fl + pidx * 28;
        half4 hU, hH, hD;
#pragma unroll
        for (int i = 0; i < 4; ++i) {
            hU[i] = (_Float16)fU[i];
            hH[i] = (_Float16)fH[i];
            hD[i] = (_Float16)fD[i];
        }
        *(half4*)(row + hf * 4)      = hU;
        *(half4*)(row + 8 + hf * 4)  = hH;
        *(half4*)(row + 16 + hf * 4) = hD;
    }
    __syncthreads();

    // ---- MLP: wave owns 32 points, j-tiles {0,1} ----
    floatx4 zf; zf[0] = 0.f; zf[1] = 0.f; zf[2] = 0.f; zf[3] = 0.f;
    const _Float16* wb = fl + (size_t)wv * 32 * 28;
    const _Float16* w0l = wl;
    const _Float16* w1l = wl + 768;
    const _Float16* w2l = wl + 1920;
    const _Float16* w3l = wl + 3072;

    half4 b0[2], b1[2];
#pragma unroll
    for (int j = 0; j < 2; ++j) {
        const _Float16* r = wb + (size_t)(j * 16 + c15) * 28;
        b0[j] = *(const half4*)(r + q * 4);
        b1[j] = (q < 2) ? *(const half4*)(r + 16 + q * 4) : zero4();
    }

    floatx4 cc[2][2];
#pragma unroll
    for (int m = 0; m < 2; ++m) {
        half4 a0 = *(const half4*)(w0l + (size_t)(16 * m + c15) * 24 + q * 4);
        half4 a1 = (q < 2) ? *(const half4*)(w0l + (size_t)(16 * m + c15) * 24 + 16 + q * 4) : zero4();
#pragma unroll
        for (int j = 0; j < 2; ++j)
            cc[m][j] = mfma16(a1, b1[j], mfma16(a0, b0[j], zf));
    }
#pragma unroll
    for (int j = 0; j < 2; ++j)
#pragma unroll
        for (int e = 0; e < 4; ++e) {
            b0[j][e] = (_Float16)fmaxf(cc[0][j][e], 0.f);
            b1[j][e] = (_Float16)fmaxf(cc[1][j][e], 0.f);
        }

#pragma unroll
    for (int m = 0; m < 2; ++m) {
        half4 a0 = *(const half4*)(w1l + (size_t)(16 * m + c15) * 36 + q * 4);
        half4 a1 = *(const half4*)(w1l + (size_t)(16 * m + c15) * 36 + 16 + q * 4);
#pragma unroll
        for (int j = 0; j < 2; ++j)
            cc[m][j] = mfma16(a1, b1[j], mfma16(a0, b0[j], zf));
    }
#pragma unroll
    for (int j = 0; j < 2; ++j)
#pragma unroll
        for (int e = 0; e < 4; ++e) {
            b0[j][e] = (_Float16)fmaxf(cc[0][j][e], 0.f);
            b1[j][e] = (_Float16)fmaxf(cc[1][j][e], 0.f);
        }

#pragma unroll
    for (int m = 0; m < 2; ++m) {
        half4 a0 = *(const half4*)(w2l + (size_t)(16 * m + c15) * 36 + q * 4);
        half4 a1 = *(const half4*)(w2l + (size_t)(16 * m + c15) * 36 + 16 + q * 4);
#pragma unroll
        for (int j = 0; j < 2; ++j)
            cc[m][j] = mfma16(a1, b1[j], mfma16(a0, b0[j], zf));
    }
#pragma unroll
    for (int j = 0; j < 2; ++j)
#pragma unroll
        for (int e = 0; e < 4; ++e) {
            b0[j][e] = (_Float16)fmaxf(cc[0][j][e], 0.f);
            b1[j][e] = (_Float16)fmaxf(cc[1][j][e], 0.f);
        }

    floatx4 c3[2];
    {
        half4 a0 = *(const half4*)(w3l + (size_t)c15 * 36 + q * 4);
        half4 a1 = *(const half4*)(w3l + (size_t)c15 * 36 + 16 + q * 4);
#pragma unroll
        for (int j = 0; j < 2; ++j)
            c3[j] = mfma16(a1, b1[j], mfma16(a0, b0[j], zf));
    }

    if (lane < 16) {
        const size_t base = (size_t)blockIdx.x * 128 + (size_t)wv * 32;
#pragma unroll
        for (int j = 0; j < 2; ++j) {
            size_t p = base + (size_t)j * 16 + lane;
            float* o = out + p * 3;
            o[0] = c3[j][0];
            o[1] = c3[j][1];
            o[2] = c3[j][2];
        }
    }
}

extern "C" void kernel_launch(void* const* d_in, const int* in_sizes, int n_in,
                              void* d_out, int out_size, void* d_ws, size_t ws_size,
                              hipStream_t stream) {
    const float* x       = (const float*)d_in[0];
    const float* u_plane = (const float*)d_in[1];
    const float* h_plane = (const float*)d_in[2];
    const float* d_plane = (const float*)d_in[3];
    const float* W0      = (const float*)d_in[4];
    const float* W1      = (const float*)d_in[5];
    const float* W2      = (const float*)d_in[6];
    const float* W3      = (const float*)d_in[7];
    float* out = (float*)d_out;
    _Float16* wsw = (_Float16*)d_ws;

    wprep_kernel<<<1, 256, 0, stream>>>(W0, W1, W2, W3, wsw);

    int n = in_sizes[0] / 6;          // 2^21
    int grid = n / 128;               // 128 points per block
    tpmlp_kernel<<<grid, 256, 0, stream>>>(x, u_plane, h_plane, d_plane, wsw, out);
}